// Round 3
// baseline (193.224 us; speedup 1.0000x reference)
//
#include <hip/hip_runtime.h>
#include <hip/hip_bf16.h>
#include <stdint.h>

#define B_   64
#define L_   4096
#define H_   128
#define HG_  32            // h-channels per block
#define NG_  4             // h-groups
#define TI_  256           // timesteps per iteration
#define NIT_ 16            // iterations (L/TI)
#define PADI 136           // bf16 row stride for inp tile
// swizzle: bijective in h for fixed t; bit4 = t4^t2 varies with quad in the
// epilogue write (t = tile*16 + quad*4 + e) -> writes spread across both
// 16-bank halves (2-way, free) instead of 4-way.
#define SW(t) ((((t) << 2) ^ (t)) & 31)

typedef __attribute__((ext_vector_type(8))) short short8;
typedef __attribute__((ext_vector_type(4))) float floatx4;
typedef __attribute__((ext_vector_type(2))) float floatx2;

#define LOG2E 1.44269504088896340736f

__device__ __forceinline__ unsigned short f2bf(float f){
    unsigned int u = __float_as_uint(f);
    u += 0x7FFFu + ((u >> 16) & 1u);      // RNE
    return (unsigned short)(u >> 16);
}
__device__ __forceinline__ float bf2f(unsigned short s){
    return __uint_as_float(((unsigned int)s) << 16);
}
__device__ __forceinline__ unsigned int pack2(float lo, float hi){
    __hip_bfloat162 h = __float22bfloat162_rn(make_float2(lo, hi));
    return *reinterpret_cast<unsigned int*>(&h);
}

// Fused full-timeline kernel. 256 blocks x 1024 threads, 1 block/CU.
// Block (bb, g): batch row bb, h-channels [g*32, g*32+32). Register carry.
// 4 barriers/iter: A(inp)|B(mfma+gates)|C1(seg scan)|C2(Kogge) ; C3 (replay +
// in-wave y-reduce + global store) runs barrier-free into next A.
__global__ __launch_bounds__(1024, 4)
void fused_rnn(const float* __restrict__ x,
               const float* __restrict__ Wp, const float* __restrict__ bp,
               const float* __restrict__ Wz, const float* __restrict__ bz,
               const float* __restrict__ Wh, const float* __restrict__ bh,
               const float* __restrict__ Wg,
               float* __restrict__ partials)
{
    __shared__ __align__(16) unsigned short s_inp[TI_*PADI];  // 69632 B (weight staging reuses this)
    __shared__ __align__(16) unsigned int  s_ab[TI_*HG_];     // 32768 B (a,th) bf16 pairs
    __shared__ __align__(16) floatx2 s_agg[32*32];            // 8192 B seg aggregates
    __shared__ float s_hh[32*32];                             // 4096 B seg-entry h values

    const int bid = blockIdx.x;
    const int bb  = bid >> 2;
    const int g   = bid & 3;
    const int tid = threadIdx.x;
    const int wv = tid >> 6, lane = tid & 63, quad = lane >> 4, l15 = lane & 15;

    // --- roles ---
    const int G   = wv >> 3;          // 0: z-gate wave, 1: h-gate wave
    const int tt0 = wv & 7;           // handles t-tiles tt0 and tt0+8
    const int sh  = tid & 31;         // C1/C3: h index
    const int ss  = tid >> 5;         // C1/C3: seg index (8 t each)
    const int rh  = tid >> 5;         // C2: h index (remapped: segs in-lane)
    const int rs  = tid & 31;         // C2: seg index
    const int cg  = tid & 31;         // inp: col group (4 cols)
    const int tg  = tid >> 5;         // inp: t group (8 t)

    // ---- in-kernel weight prep: Wz/Wh -> bf16 [gate][nn][k] in s_inp area ----
    {
        unsigned short* s_w = s_inp;
        const int gate = tid >> 9;            // 0:z 1:h
        const int r    = tid & 511;
        const int k    = r >> 2;              // 0..127
        const int nn0  = (r & 3) * 8;         // 0,8,16,24
        const float* Wsrc = gate ? Wh : Wz;
        const float* p = Wsrc + (size_t)k*H_ + g*HG_ + nn0;
        floatx4 a = *(const floatx4*)p;
        floatx4 b = *(const floatx4*)(p + 4);
        #pragma unroll
        for (int j = 0; j < 4; ++j){
            s_w[gate*4096 + (nn0+j)*H_ + k]   = f2bf(a[j]);
            s_w[gate*4096 + (nn0+4+j)*H_ + k] = f2bf(b[j]);
        }
    }
    __syncthreads();

    // ---- one-time register preloads (frags from staged LDS) ----
    short8 bfr[2][4];
    {
        const unsigned short* wbase = s_inp + G*4096;
        #pragma unroll
        for (int ct = 0; ct < 2; ++ct)
            #pragma unroll
            for (int kk = 0; kk < 4; ++kk)
                bfr[ct][kk] = *(const short8*)&wbase[(ct*16 + l15)*H_ + kk*32 + quad*8];
    }
    float biasv[2];
    #pragma unroll
    for (int ct = 0; ct < 2; ++ct)
        biasv[ct] = (G ? bh : bz)[g*HG_ + ct*16 + l15];
    const float wgv = Wg[g*HG_ + sh];
    float w0[4], w1[4], w2[4], bc[4];
    #pragma unroll
    for (int m = 0; m < 4; ++m){
        w0[m] = Wp[cg*4+m]; w1[m] = Wp[H_+cg*4+m]; w2[m] = Wp[2*H_+cg*4+m];
        bc[m] = bp[cg*4+m];
    }
    float h_run = 0.0f;               // carry (consistent across each 32-lane group)
    __syncthreads();                  // frag reads done before s_inp reuse

    // ---- x prefetch (registers survive barriers; 6x dwordx4, coalesced) ----
    const float* xbase = x + ((size_t)bb*L_ + tg*8)*3;
    floatx4 xr[6];
    #pragma unroll
    for (int q = 0; q < 6; ++q) xr[q] = *(const floatx4*)(xbase + q*4);

    for (int it = 0; it < NIT_; ++it){
        // ---- phase A: inp = x @ Wp + bp -> bf16 LDS; prefetch next x ----
        {
            float xf[24];
            #pragma unroll
            for (int q = 0; q < 6; ++q){
                xf[q*4+0] = xr[q][0]; xf[q*4+1] = xr[q][1];
                xf[q*4+2] = xr[q][2]; xf[q*4+3] = xr[q][3];
            }
            if (it + 1 < NIT_){
                const float* xn = xbase + (size_t)(it+1)*(TI_*3);
                #pragma unroll
                for (int q = 0; q < 6; ++q) xr[q] = *(const floatx4*)(xn + q*4);
            }
            #pragma unroll
            for (int j = 0; j < 8; ++j){
                int t = tg*8 + j;
                float x0 = xf[j*3], x1 = xf[j*3+1], x2 = xf[j*3+2];
                float v0 = fmaf(x2, w2[0], fmaf(x1, w1[0], fmaf(x0, w0[0], bc[0])));
                float v1 = fmaf(x2, w2[1], fmaf(x1, w1[1], fmaf(x0, w0[1], bc[1])));
                float v2 = fmaf(x2, w2[2], fmaf(x1, w1[2], fmaf(x0, w0[2], bc[2])));
                float v3 = fmaf(x2, w2[3], fmaf(x1, w1[3], fmaf(x0, w0[3], bc[3])));
                uint2 st; st.x = pack2(v0, v1); st.y = pack2(v2, v3);
                *(uint2*)&s_inp[t*PADI + cg*4] = st;
            }
        }
        __syncthreads();   // BAR1

        // ---- phase B: MFMA (one gate per wave, 2 t-tiles) + epilogue -> s_ab ----
        #pragma unroll
        for (int tl = 0; tl < 2; ++tl){
            int tile = tt0 + tl*8;
            floatx4 acc0 = (floatx4){0.f,0.f,0.f,0.f};
            floatx4 acc1 = (floatx4){0.f,0.f,0.f,0.f};
            #pragma unroll
            for (int kk = 0; kk < 4; ++kk){
                short8 af = *(const short8*)&s_inp[(tile*16 + l15)*PADI + kk*32 + quad*8];
                acc0 = __builtin_amdgcn_mfma_f32_16x16x32_bf16(af, bfr[0][kk], acc0, 0, 0, 0);
                acc1 = __builtin_amdgcn_mfma_f32_16x16x32_bf16(af, bfr[1][kk], acc1, 0, 0, 0);
            }
            #pragma unroll
            for (int ct = 0; ct < 2; ++ct){
                floatx4 acc = ct ? acc1 : acc0;
                int hl = ct*16 + l15;
                #pragma unroll
                for (int e = 0; e < 4; ++e){
                    int t = tile*16 + quad*4 + e;
                    float v = acc[e] + biasv[ct];
                    float r;
                    if (G == 0){
                        r = __builtin_amdgcn_rcpf(1.0f + __builtin_amdgcn_exp2f(v * LOG2E)); // a = 1-z
                    } else {
                        float ex = __builtin_amdgcn_exp2f(2.0f*LOG2E*v);
                        r = 1.0f - 2.0f*__builtin_amdgcn_rcpf(ex + 1.0f);                    // tanh
                    }
                    ((unsigned short*)s_ab)[(t*HG_ + (hl ^ SW(t)))*2 + G] = f2bf(r);
                }
            }
        }
        __syncthreads();   // BAR2

        // ---- phase C1: per-seg local scan (8 t), a/b kept in regs ----
        float aj[8], bj[8];
        {
            float A = 1.0f, Q = 0.0f;
            #pragma unroll
            for (int j = 0; j < 8; ++j){
                int t = ss*8 + j;
                unsigned int u = s_ab[t*HG_ + (sh ^ SW(t))];
                float a  = bf2f((unsigned short)(u & 0xffffu));
                float th = bf2f((unsigned short)(u >> 16));
                float b  = fmaf(-a, th, th);          // (1-a)*th
                aj[j] = a; bj[j] = b;
                Q = fmaf(a, Q, b);
                A *= a;
            }
            s_agg[ss*32 + (sh ^ ss)] = (floatx2){A, Q};
        }
        __syncthreads();   // BAR3

        // ---- phase C2: Kogge-Stone over 32 segs (remapped: segs in-lane) ----
        {
            floatx2 v = s_agg[rs*32 + (rh ^ rs)];
            float P = v[0], Hq = v[1];
            #pragma unroll
            for (int d = 1; d < 32; d <<= 1){
                float pP = __shfl_up(P, d, 32);
                float pH = __shfl_up(Hq, d, 32);
                if (rs >= d){
                    Hq = fmaf(P, pH, Hq);
                    P  = P * pP;
                }
            }
            float eP = __shfl_up(P, 1, 32);
            float eH = __shfl_up(Hq, 1, 32);
            if (rs == 0){ eP = 1.0f; eH = 0.0f; }
            float tP = __shfl(P, 31, 32);
            float tH = __shfl(Hq, 31, 32);
            s_hh[rs*32 + (rh ^ rs)] = fmaf(eP, h_run, eH);   // h at seg entry - 1
            h_run = fmaf(tP, h_run, tH);                     // carry to next iter
        }
        __syncthreads();   // BAR4

        // ---- phase C3: replay 8 steps, in-wave y-reduce over h, store ----
        {
            float hh = s_hh[ss*32 + (sh ^ ss)];
            float y[8];
            #pragma unroll
            for (int j = 0; j < 8; ++j){
                y[j] = wgv * hh;
                hh = fmaf(aj[j], hh, bj[j]);
            }
            #pragma unroll
            for (int d = 16; d >= 1; d >>= 1)
                #pragma unroll
                for (int j = 0; j < 8; ++j)
                    y[j] += __shfl_xor(y[j], d, 32);
            if (sh == 0){
                float* dst = partials + (size_t)(g*B_ + bb)*L_ + it*TI_ + ss*8;
                *(floatx4*)dst     = (floatx4){y[0], y[1], y[2], y[3]};
                *(floatx4*)(dst+4) = (floatx4){y[4], y[5], y[6], y[7]};
            }
        }
        // no barrier: C3 touches only s_hh (rewritten 3 barriers later) + regs
    }
}

// Gather: preds = bg + sum of 4 group partials (float4-vectorized). 64 blocks.
__global__ __launch_bounds__(1024)
void gather(const floatx4* __restrict__ partials, const float* __restrict__ bg,
            floatx4* __restrict__ preds)
{
    size_t i = (size_t)blockIdx.x*1024 + threadIdx.x;       // 0 .. 65535
    const size_t S = (size_t)B_ * L_ / 4;                   // 65536
    float b = bg[0];
    floatx4 v = partials[i] + partials[S+i] + partials[2*S+i] + partials[3*S+i];
    v[0] += b; v[1] += b; v[2] += b; v[3] += b;
    preds[i] = v;
}

extern "C" void kernel_launch(void* const* d_in, const int* in_sizes, int n_in,
                              void* d_out, int out_size, void* d_ws, size_t ws_size,
                              hipStream_t stream){
    const float* x  = (const float*)d_in[0];
    const float* Wp = (const float*)d_in[1];
    const float* bp = (const float*)d_in[2];
    const float* Wz = (const float*)d_in[3];
    const float* bz = (const float*)d_in[4];
    const float* Wh = (const float*)d_in[5];
    const float* bh = (const float*)d_in[6];
    const float* Wg = (const float*)d_in[7];
    const float* bg = (const float*)d_in[8];
    float* preds = (float*)d_out;

    uint8_t* w8 = (uint8_t*)d_ws;
    float* partials = (float*)w8;                           // 4 MB: [g][bb][l] f32

    hipLaunchKernelGGL(fused_rnn, dim3(B_*NG_), dim3(1024), 0, stream,
                       x, Wp, bp, Wz, bz, Wh, bh, Wg, partials);
    hipLaunchKernelGGL(gather, dim3(B_*L_/4096), dim3(1024), 0, stream,
                       (const floatx4*)partials, bg, (floatx4*)preds);
}